// Round 7
// baseline (404.648 us; speedup 1.0000x reference)
//
#include <hip/hip_runtime.h>
#include <hip/hip_bf16.h>

typedef _Float16 half8 __attribute__((ext_vector_type(8)));
typedef float floatx4 __attribute__((ext_vector_type(4)));

#define NEDGE 200000
#define ETOT  400000
#define BM 128
#define NTILES (ETOT / BM)   /* 3125 exact */

__device__ _Float16 g_w1[256 * 256];       // [n][k] fp16 (transposed W1)
__device__ _Float16 g_w2[256 * 256];       // [n][k] fp16 (transposed W2)
__device__ _Float16 g_xh[100000L * 256];   // fp16 x (51.2 MB)
__device__ _Float16 g_e[(long)ETOT * 256]; // fp16 e = x[s]*x[d] (204.8 MB)

__global__ void prep_weights(const float* __restrict__ W1, const float* __restrict__ W2) {
    int t = blockIdx.x * 256 + threadIdx.x;   // t = k*256 + n
    int k = t >> 8, n = t & 255;
    g_w1[n * 256 + k] = (_Float16)W1[t];
    g_w2[n * 256 + k] = (_Float16)W2[t];
}

__global__ void prep_x(const float* __restrict__ x) {
    long i = ((long)blockIdx.x * 256 + threadIdx.x) * 8;  // 12500 blocks exact
    floatx4 v0 = *(const floatx4*)(x + i);
    floatx4 v1 = *(const floatx4*)(x + i + 4);
    half8 h;
    h[0] = (_Float16)v0[0]; h[1] = (_Float16)v0[1];
    h[2] = (_Float16)v0[2]; h[3] = (_Float16)v0[3];
    h[4] = (_Float16)v1[0]; h[5] = (_Float16)v1[1];
    h[6] = (_Float16)v1[2]; h[7] = (_Float16)v1[3];
    *(half8*)(g_xh + i) = h;
}

// ---- K2: pure gather + product, max occupancy, no LDS/barriers ----
__global__ __launch_bounds__(256) void gather_product(
    const int* __restrict__ psrc, const int* __restrict__ pdst,
    const int* __restrict__ nsrc, const int* __restrict__ ndst)
{
    int gid = blockIdx.x * 256 + threadIdx.x;
    int e = gid >> 5;
    int c = (gid & 31) * 8;
    int s, d;
    if (e < NEDGE) { s = psrc[e]; d = pdst[e]; }
    else           { s = nsrc[e - NEDGE]; d = ndst[e - NEDGE]; }
    half8 a = *(const half8*)(g_xh + (long)s * 256 + c);
    half8 b = *(const half8*)(g_xh + (long)d * 256 + c);
    *(half8*)(g_e + (long)e * 256 + c) = a * b;
}

// async global->LDS, 16B/lane
#define GLOAD_LDS16(g, l) \
    __builtin_amdgcn_global_load_lds((const __attribute__((address_space(1))) unsigned int*)(g), \
                                     (__attribute__((address_space(3))) unsigned int*)(l), 16, 0, 0)

// ---- K3: MLP over linear e tiles — 512 threads, 8 waves (2M x 4N) ----
__global__ __launch_bounds__(512, 2) void mlp(
    const float* __restrict__ b1, const float* __restrict__ b2,
    const float* __restrict__ W3, const float* __restrict__ b3,
    float* __restrict__ out)
{
    __shared__ _Float16 eT[BM * 256];   // 64KB, rows XOR-swizzled
    __shared__ float part[BM * 4];

    const int tid  = threadIdx.x;
    const int lane = tid & 63;
    const int wid  = tid >> 6;     // 0..7
    const int mr   = wid >> 2;     // 0..1: row half [mr*64, +64)
    const int nc   = wid & 3;      // 0..3: col quarter
    const int n0   = nc * 64;
    const int l15  = lane & 15;
    const int lhi  = lane >> 4;

    // stage e-tile: wave w loads rows [w*16, w*16+16), 2 rows per gload_lds.
    // LDS dest linear; source chunk pre-swizzled by ^(row&7) (rule 21).
    {
        const long ebase = (long)blockIdx.x * BM * 256;
        const int half = lane >> 5;             // 0,1
        const int ch   = lane & 31;
        #pragma unroll
        for (int j = 0; j < 8; ++j) {
            int r2  = wid * 16 + 2 * j;
            int row = r2 + half;
            const char* g = (const char*)(g_e + ebase + (long)row * 256)
                          + ((ch ^ (row & 7)) * 16);
            GLOAD_LDS16(g, (char*)eT + r2 * 512);
        }
        asm volatile("s_waitcnt vmcnt(0)" ::: "memory");
    }
    __syncthreads();

    const unsigned alin = (unsigned)((mr * 64 + l15) * 512 + lhi * 16);
    const unsigned aswz = (unsigned)((l15 & 7) << 4);

    floatx4 acc[4][4];

    // ---------------- layer 1 ----------------
    #pragma unroll
    for (int mi = 0; mi < 4; ++mi)
        #pragma unroll
        for (int ni = 0; ni < 4; ++ni)
            acc[mi][ni] = (floatx4){0.f, 0.f, 0.f, 0.f};
    {
        const _Float16* __restrict__ wb = g_w1 + (n0 + l15) * 256 + lhi * 8;
        half8 bcur[4], bnext[4];
        #pragma unroll
        for (int ni = 0; ni < 4; ++ni) bcur[ni] = *(const half8*)(wb + ni * 4096);
        #pragma unroll
        for (int kk = 0; kk < 8; ++kk) {
            if (kk < 7) {
                #pragma unroll
                for (int ni = 0; ni < 4; ++ni)
                    bnext[ni] = *(const half8*)(wb + ni * 4096 + (kk + 1) * 32);
            }
            #pragma unroll
            for (int mi = 0; mi < 4; ++mi) {
                half8 a = *(const half8*)((char*)eT + ((alin + mi * 8192 + kk * 64) ^ aswz));
                #pragma unroll
                for (int ni = 0; ni < 4; ++ni)
                    acc[mi][ni] = __builtin_amdgcn_mfma_f32_16x16x32_f16(a, bcur[ni], acc[mi][ni], 0, 0, 0);
            }
            #pragma unroll
            for (int ni = 0; ni < 4; ++ni) bcur[ni] = bnext[ni];
        }
    }
    // bias + relu, write h1 back (same swizzle)
    {
        float b1v[4];
        #pragma unroll
        for (int ni = 0; ni < 4; ++ni) b1v[ni] = b1[n0 + ni * 16 + l15];
        __syncthreads();
        #pragma unroll
        for (int mi = 0; mi < 4; ++mi)
            #pragma unroll
            for (int ni = 0; ni < 4; ++ni)
                #pragma unroll
                for (int r = 0; r < 4; ++r) {
                    float h = fmaxf(acc[mi][ni][r] + b1v[ni], 0.f);
                    int row = mr * 64 + mi * 16 + lhi * 4 + r;
                    int col = n0 + ni * 16 + l15;
                    unsigned addr = ((unsigned)(row * 512 + col * 2)) ^ ((unsigned)((row & 7) << 4));
                    *(_Float16*)((char*)eT + addr) = (_Float16)h;
                }
        __syncthreads();
    }

    // ---------------- layer 2 ----------------
    #pragma unroll
    for (int mi = 0; mi < 4; ++mi)
        #pragma unroll
        for (int ni = 0; ni < 4; ++ni)
            acc[mi][ni] = (floatx4){0.f, 0.f, 0.f, 0.f};
    {
        const _Float16* __restrict__ wb = g_w2 + (n0 + l15) * 256 + lhi * 8;
        half8 bcur[4], bnext[4];
        #pragma unroll
        for (int ni = 0; ni < 4; ++ni) bcur[ni] = *(const half8*)(wb + ni * 4096);
        #pragma unroll
        for (int kk = 0; kk < 8; ++kk) {
            if (kk < 7) {
                #pragma unroll
                for (int ni = 0; ni < 4; ++ni)
                    bnext[ni] = *(const half8*)(wb + ni * 4096 + (kk + 1) * 32);
            }
            #pragma unroll
            for (int mi = 0; mi < 4; ++mi) {
                half8 a = *(const half8*)((char*)eT + ((alin + mi * 8192 + kk * 64) ^ aswz));
                #pragma unroll
                for (int ni = 0; ni < 4; ++ni)
                    acc[mi][ni] = __builtin_amdgcn_mfma_f32_16x16x32_f16(a, bcur[ni], acc[mi][ni], 0, 0, 0);
            }
            #pragma unroll
            for (int ni = 0; ni < 4; ++ni) bcur[ni] = bnext[ni];
        }
    }

    // ---------------- layer 3 ----------------
    float w3v[4], b2v[4];
    #pragma unroll
    for (int ni = 0; ni < 4; ++ni) {
        b2v[ni] = b2[n0 + ni * 16 + l15];
        w3v[ni] = W3[n0 + ni * 16 + l15];
    }
    __syncthreads();
    #pragma unroll
    for (int mi = 0; mi < 4; ++mi)
        #pragma unroll
        for (int r = 0; r < 4; ++r) {
            float s = 0.f;
            #pragma unroll
            for (int ni = 0; ni < 4; ++ni)
                s += fmaxf(acc[mi][ni][r] + b2v[ni], 0.f) * w3v[ni];
            s += __shfl_xor(s, 1);
            s += __shfl_xor(s, 2);
            s += __shfl_xor(s, 4);
            s += __shfl_xor(s, 8);
            if (l15 == 0) {
                int row = mr * 64 + mi * 16 + lhi * 4 + r;
                part[row * 4 + nc] = s;
            }
        }
    __syncthreads();
    if (tid < BM) {
        floatx4 p = *(const floatx4*)(part + tid * 4);
        out[blockIdx.x * BM + tid] = p[0] + p[1] + p[2] + p[3] + b3[0];
    }
}

extern "C" void kernel_launch(void* const* d_in, const int* in_sizes, int n_in,
                              void* d_out, int out_size, void* d_ws, size_t ws_size,
                              hipStream_t stream) {
    const float* x    = (const float*)d_in[0];
    const int* psrc   = (const int*)d_in[1];
    const int* pdst   = (const int*)d_in[2];
    const int* nsrc   = (const int*)d_in[3];
    const int* ndst   = (const int*)d_in[4];
    const float* W1   = (const float*)d_in[5];
    const float* b1   = (const float*)d_in[6];
    const float* W2   = (const float*)d_in[7];
    const float* b2   = (const float*)d_in[8];
    const float* W3   = (const float*)d_in[9];
    const float* b3   = (const float*)d_in[10];

    prep_weights<<<256, 256, 0, stream>>>(W1, W2);
    prep_x<<<12500, 256, 0, stream>>>(x);
    gather_product<<<ETOT / 8, 256, 0, stream>>>(psrc, pdst, nsrc, ndst);
    mlp<<<NTILES, 512, 0, stream>>>(b1, b2, W3, b3, (float*)d_out);
}